// Round 1
// baseline (1371.004 us; speedup 1.0000x reference)
//
#include <hip/hip_runtime.h>
#include <cmath>

// ---------------------------------------------------------------------------
// SpatialLinearAttention, fp32 baseline.
//   x:(2,256,16,64,64)  w_qkv:(768,256)  w_out:(256,256)  b_out:(256,)
// Per frame (32 frames = b*f):
//   K1: qkv[768,4096] = w_qkv @ xr          (xr[c][n] = x[b][c][f][n])
//   K2: softmax over n for k rows (in place)
//   K3: softmax over d (32) for q cols, * 1/sqrt(32) (in place)
//   K4: context_h = k_h @ v_h^T (32x32); fold into W2[o][h*32+d]
//       = sum_e w_out[o][h*32+e] * context_h[d][e]      (256x256 per frame)
//   K5: y = W2 @ q + b_out, stored transposed to out[b][o][f][n]
// The W2 fold removes the bhen intermediate GEMM + 128MiB of traffic.
// ---------------------------------------------------------------------------

#define NSP   4096          // spatial n = 64*64
#define NQKV  768
#define XCH_STRIDE 65536    // x stride over c: 16*4096
#define XB_STRIDE  16777216 // x stride over b: 256*16*4096

// ---------------- K1: qkv = w_qkv @ xr (per frame), 64x64 tile, BK=16 -------
__global__ __launch_bounds__(256) void k_qkv_gemm(const float* __restrict__ x,
                                                  const float* __restrict__ w_qkv,
                                                  float* __restrict__ qkv, int fr0)
{
    const int tid = threadIdx.x;
    const int n0 = blockIdx.x * 64;
    const int o0 = blockIdx.y * 64;
    const int fl = blockIdx.z;
    const int frame = fr0 + fl;
    const int b = frame >> 4, f = frame & 15;
    const float* xbase = x + (size_t)b * XB_STRIDE + (size_t)f * NSP;

    __shared__ float As[16][64];   // [k][o]  (w_qkv tile, transposed on store)
    __shared__ float Bs[16][64];   // [k][n]

    float acc[4][4] = {};
    const int tx = tid & 15, ty = tid >> 4;

    const int ar = tid >> 2;          // o row within tile (0..63)
    const int ak = (tid & 3) * 4;     // k offset
    const int br = tid >> 4;          // k row (0..15)
    const int bc = (tid & 15) * 4;    // n offset

    for (int kk = 0; kk < 256; kk += 16) {
        float4 av = *(const float4*)&w_qkv[(size_t)(o0 + ar) * 256 + kk + ak];
        float4 bv = *(const float4*)&xbase[(size_t)(kk + br) * XCH_STRIDE + n0 + bc];
        __syncthreads();
        As[ak+0][ar] = av.x; As[ak+1][ar] = av.y; As[ak+2][ar] = av.z; As[ak+3][ar] = av.w;
        *(float4*)&Bs[br][bc] = bv;
        __syncthreads();
        #pragma unroll
        for (int k = 0; k < 16; ++k) {
            float4 a4 = *(const float4*)&As[k][ty*4];
            float4 b4 = *(const float4*)&Bs[k][tx*4];
            float a[4] = {a4.x, a4.y, a4.z, a4.w};
            float bb[4] = {b4.x, b4.y, b4.z, b4.w};
            #pragma unroll
            for (int i = 0; i < 4; ++i)
                #pragma unroll
                for (int j = 0; j < 4; ++j)
                    acc[i][j] = fmaf(a[i], bb[j], acc[i][j]);
        }
    }
    float* obase = qkv + (size_t)fl * NQKV * NSP;
    #pragma unroll
    for (int i = 0; i < 4; ++i) {
        float4 v = make_float4(acc[i][0], acc[i][1], acc[i][2], acc[i][3]);
        *(float4*)&obase[(size_t)(o0 + ty*4 + i) * NSP + n0 + tx*4] = v;
    }
}

// ---------------- K2: softmax over n=4096 for each k row (in place) ---------
__global__ __launch_bounds__(256) void k_softmax_k(float* __restrict__ qkv)
{
    const int row = blockIdx.x;  // 0..255 = h*32+d
    const int fl  = blockIdx.y;
    float* p = qkv + ((size_t)fl * NQKV + 256 + row) * (size_t)NSP;
    const int tid = threadIdx.x;

    float v[16];
    float m = -1e30f;
    #pragma unroll
    for (int i = 0; i < 16; ++i) { v[i] = p[tid + i*256]; m = fmaxf(m, v[i]); }
    #pragma unroll
    for (int off = 32; off > 0; off >>= 1) m = fmaxf(m, __shfl_down(m, off));
    __shared__ float redm[4];
    if ((tid & 63) == 0) redm[tid >> 6] = m;
    __syncthreads();
    m = fmaxf(fmaxf(redm[0], redm[1]), fmaxf(redm[2], redm[3]));

    float s = 0.f;
    #pragma unroll
    for (int i = 0; i < 16; ++i) { v[i] = expf(v[i] - m); s += v[i]; }
    #pragma unroll
    for (int off = 32; off > 0; off >>= 1) s += __shfl_down(s, off);
    __shared__ float reds[4];
    if ((tid & 63) == 0) reds[tid >> 6] = s;
    __syncthreads();
    s = reds[0] + reds[1] + reds[2] + reds[3];
    const float inv = 1.0f / s;
    #pragma unroll
    for (int i = 0; i < 16; ++i) p[tid + i*256] = v[i] * inv;
}

// ---------------- K3: softmax over d=32 for q columns, * scale (in place) ---
__global__ __launch_bounds__(256) void k_softmax_q(float* __restrict__ qkv)
{
    const int n  = blockIdx.x * 256 + threadIdx.x;
    const int fl = blockIdx.y;
    float* base = qkv + (size_t)fl * NQKV * NSP;
    const float scale = 0.17677669529663687f; // 32^-0.5
    for (int h = 0; h < 8; ++h) {
        float v[32];
        float m = -1e30f;
        #pragma unroll
        for (int d = 0; d < 32; ++d) {
            v[d] = base[(size_t)(h*32 + d) * NSP + n];
            m = fmaxf(m, v[d]);
        }
        float s = 0.f;
        #pragma unroll
        for (int d = 0; d < 32; ++d) { v[d] = expf(v[d] - m); s += v[d]; }
        const float inv = scale / s;
        #pragma unroll
        for (int d = 0; d < 32; ++d) base[(size_t)(h*32 + d) * NSP + n] = v[d] * inv;
    }
}

// ---------------- K4: context (32x32 per head) + fold into W2 ---------------
__global__ __launch_bounds__(256) void k_context_w2(const float* __restrict__ qkv,
                                                    const float* __restrict__ w_out,
                                                    float* __restrict__ w2)
{
    const int h  = blockIdx.x;   // 0..7
    const int fl = blockIdx.y;
    const int tid = threadIdx.x;
    const float* kbase = qkv + ((size_t)fl * NQKV + 256 + h*32) * (size_t)NSP;
    const float* vbase = qkv + ((size_t)fl * NQKV + 512 + h*32) * (size_t)NSP;

    __shared__ float Ks[32][68];  // stride 68: float4-aligned, d-varying banks
    __shared__ float Vs[32][68];
    __shared__ float Cs[32][33];

    const int d  = tid >> 3;        // 0..31
    const int e4 = (tid & 7) * 4;   // 0..28
    float acc[4] = {0.f, 0.f, 0.f, 0.f};

    const int lr = tid >> 3;        // load row 0..31
    const int lc = (tid & 7) * 8;   // load col 0..56

    for (int nt = 0; nt < NSP; nt += 64) {
        float4 k0 = *(const float4*)&kbase[(size_t)lr * NSP + nt + lc];
        float4 k1 = *(const float4*)&kbase[(size_t)lr * NSP + nt + lc + 4];
        float4 v0 = *(const float4*)&vbase[(size_t)lr * NSP + nt + lc];
        float4 v1 = *(const float4*)&vbase[(size_t)lr * NSP + nt + lc + 4];
        __syncthreads();
        *(float4*)&Ks[lr][lc]   = k0; *(float4*)&Ks[lr][lc+4] = k1;
        *(float4*)&Vs[lr][lc]   = v0; *(float4*)&Vs[lr][lc+4] = v1;
        __syncthreads();
        #pragma unroll
        for (int nn = 0; nn < 64; nn += 4) {
            float4 kd = *(const float4*)&Ks[d][nn];
            #pragma unroll
            for (int j = 0; j < 4; ++j) {
                float4 vv = *(const float4*)&Vs[e4 + j][nn];
                acc[j] = fmaf(kd.x, vv.x, acc[j]);
                acc[j] = fmaf(kd.y, vv.y, acc[j]);
                acc[j] = fmaf(kd.z, vv.z, acc[j]);
                acc[j] = fmaf(kd.w, vv.w, acc[j]);
            }
        }
    }
    #pragma unroll
    for (int j = 0; j < 4; ++j) Cs[d][e4 + j] = acc[j];
    __syncthreads();

    // W2[o][h*32+d] = sum_e w_out[o][h*32+e] * Cs[d][e];  o = tid
    const int o = tid;
    float acc2[32];
    #pragma unroll
    for (int dd = 0; dd < 32; ++dd) acc2[dd] = 0.f;
    for (int e = 0; e < 32; ++e) {
        const float wv = w_out[(size_t)o * 256 + h*32 + e];
        #pragma unroll
        for (int dd = 0; dd < 32; ++dd)
            acc2[dd] = fmaf(wv, Cs[dd][e], acc2[dd]);
    }
    float* wp = w2 + ((size_t)fl * 256 + o) * 256 + h*32;
    #pragma unroll
    for (int dd = 0; dd < 32; ++dd) wp[dd] = acc2[dd];
}

// ---------------- K5: y = W2 @ q + b_out, stored to out[b][o][f][n] ---------
__global__ __launch_bounds__(256) void k_out_gemm(const float* __restrict__ qkv,
                                                  const float* __restrict__ w2,
                                                  const float* __restrict__ b_out,
                                                  float* __restrict__ out, int fr0)
{
    const int tid = threadIdx.x;
    const int n0 = blockIdx.x * 64;
    const int o0 = blockIdx.y * 64;
    const int fl = blockIdx.z;
    const int frame = fr0 + fl;
    const int b = frame >> 4, f = frame & 15;
    const float* A  = w2  + (size_t)fl * 256 * 256;       // [o][c2]
    const float* Bq = qkv + (size_t)fl * NQKV * NSP;      // q rows 0..255

    __shared__ float As[16][64];
    __shared__ float Bs[16][64];

    float acc[4][4] = {};
    const int tx = tid & 15, ty = tid >> 4;
    const int ar = tid >> 2;
    const int ak = (tid & 3) * 4;
    const int br = tid >> 4;
    const int bc = (tid & 15) * 4;

    for (int kk = 0; kk < 256; kk += 16) {
        float4 av = *(const float4*)&A[(size_t)(o0 + ar) * 256 + kk + ak];
        float4 bv = *(const float4*)&Bq[(size_t)(kk + br) * NSP + n0 + bc];
        __syncthreads();
        As[ak+0][ar] = av.x; As[ak+1][ar] = av.y; As[ak+2][ar] = av.z; As[ak+3][ar] = av.w;
        *(float4*)&Bs[br][bc] = bv;
        __syncthreads();
        #pragma unroll
        for (int k = 0; k < 16; ++k) {
            float4 a4 = *(const float4*)&As[k][ty*4];
            float4 b4 = *(const float4*)&Bs[k][tx*4];
            float a[4] = {a4.x, a4.y, a4.z, a4.w};
            float bb[4] = {b4.x, b4.y, b4.z, b4.w};
            #pragma unroll
            for (int i = 0; i < 4; ++i)
                #pragma unroll
                for (int j = 0; j < 4; ++j)
                    acc[i][j] = fmaf(a[i], bb[j], acc[i][j]);
        }
    }
    float* obase = out + (size_t)b * XB_STRIDE + (size_t)f * NSP;
    #pragma unroll
    for (int i = 0; i < 4; ++i) {
        const int o = o0 + ty*4 + i;
        const float bo = b_out[o];
        float4 v = make_float4(acc[i][0] + bo, acc[i][1] + bo,
                               acc[i][2] + bo, acc[i][3] + bo);
        *(float4*)&obase[(size_t)o * XCH_STRIDE + n0 + tx*4] = v;
    }
}

// ---------------------------------------------------------------------------
extern "C" void kernel_launch(void* const* d_in, const int* in_sizes, int n_in,
                              void* d_out, int out_size, void* d_ws, size_t ws_size,
                              hipStream_t stream)
{
    const float* x     = (const float*)d_in[0];
    const float* w_qkv = (const float*)d_in[1];
    const float* w_out = (const float*)d_in[2];
    const float* b_out = (const float*)d_in[3];
    float* out = (float*)d_out;

    // frames-per-chunk: largest power of two whose scratch fits ws_size.
    // per frame: qkv 768*4096*4 B + W2 256*256*4 B = 12,845,056 B
    const size_t per_frame = (size_t)NQKV * NSP * 4 + 256 * 256 * 4;
    int CF = 32;
    while (CF > 1 && (size_t)CF * per_frame > ws_size) CF >>= 1;

    float* qkv = (float*)d_ws;
    float* w2  = (float*)((char*)d_ws + (size_t)CF * NQKV * NSP * 4);

    for (int fr0 = 0; fr0 < 32; fr0 += CF) {
        k_qkv_gemm  <<<dim3(64, 12, CF), 256, 0, stream>>>(x, w_qkv, qkv, fr0);
        k_softmax_k <<<dim3(256, CF),    256, 0, stream>>>(qkv);
        k_softmax_q <<<dim3(16, CF),     256, 0, stream>>>(qkv);
        k_context_w2<<<dim3(8, CF),      256, 0, stream>>>(qkv, w_out, w2);
        k_out_gemm  <<<dim3(64, 4, CF),  256, 0, stream>>>(qkv, w2, b_out, out, fr0);
    }
}

// Round 2
// 584.345 us; speedup vs baseline: 2.3462x; 2.3462x over previous
//
#include <hip/hip_runtime.h>
#include <cmath>

// ---------------------------------------------------------------------------
// SpatialLinearAttention — bf16 MFMA for the two big GEMMs, fp32 elsewhere.
//   x:(2,256,16,64,64) f32, w_qkv:(768,256) f32, w_out:(256,256) f32, b_out:(256,)
// Pipeline per chunk of CF frames (j = fl*4096 + n, local spatial index):
//   C0: xbf_t[j][c]   = bf16(x^T)            (transpose, k-contiguous)
//   C1: wq_bf         = bf16(w_qkv)          (once)
//   K1: qkv_t[j][o]   = MFMA( wq_bf[o][c] , xbf_t[j][c] )    o=0..767, bf16 out
//   K2: softmax over j for k cols (o=256..511), per (frame,h,d), in place
//   K3: softmax over d (32) for q (o=0..255), row-local, * 1/sqrt(32), in place
//   K4: context_h[d][e] = sum_j k*v (fp32); fold W2[o][h*32+d] =
//       sum_e w_out[o][h*32+e]*C_h[d][e]; write bf16 [o][c2]
//   K5: out = MFMA( qkv_t[j][0..255] , W2[o][c2] ) + b_out, fp32 direct store
// MFMA 16x16x32 bf16: A[m=lane&15][k=quad*8+j8], B[n=lane&15][k=quad*8+j8],
// D: col(n)=lane&15, row(m)=quad*4+reg.  Both operands want k-contiguous rows.
// ---------------------------------------------------------------------------

typedef unsigned short u16;
typedef __attribute__((ext_vector_type(4))) unsigned short u16x4;
typedef __attribute__((ext_vector_type(8))) unsigned short u16x8;
typedef __attribute__((ext_vector_type(4))) unsigned int   u32x4;
typedef __attribute__((ext_vector_type(8))) short bf16x8;
typedef __attribute__((ext_vector_type(4))) float f32x4;

#define XCH_STRIDE 65536    // x stride over c: 16*4096
#define XB_STRIDE  16777216 // x stride over b: 256*16*4096

__device__ __forceinline__ float bf2f(u16 u) {
    union { unsigned int i; float f; } w; w.i = ((unsigned int)u) << 16; return w.f;
}
__device__ __forceinline__ u16 f2bf(float f) {
    union { float f; unsigned int i; } w; w.f = f;
    return (u16)((w.i + 0x7FFFu + ((w.i >> 16) & 1u)) >> 16);
}
__device__ __forceinline__ void async16(const void* g, void* l) {
    __builtin_amdgcn_global_load_lds(
        (const __attribute__((address_space(1))) unsigned int*)g,
        (__attribute__((address_space(3))) unsigned int*)l, 16, 0, 0);
}

// ---------------- C0: x (b,c,f,n) f32 -> xbf_t[(fl,n)][c] bf16 --------------
__global__ __launch_bounds__(256) void k_cvt_x(const float* __restrict__ x,
                                               u16* __restrict__ xbf, int fr0)
{
    const int tid = threadIdx.x;
    const int n0 = blockIdx.x * 64;
    const int c0 = blockIdx.y * 64;
    const int fl = blockIdx.z;
    const int frame = fr0 + fl, b = frame >> 4, f = frame & 15;
    const float* xb = x + (size_t)b * XB_STRIDE + (size_t)f * 4096;
    __shared__ float T[64][65];
    const int nn = tid & 63, cq = tid >> 6;
    #pragma unroll
    for (int r = 0; r < 16; ++r) {
        const int cl = r * 4 + cq;
        T[cl][nn] = xb[(size_t)(c0 + cl) * XCH_STRIDE + n0 + nn];
    }
    __syncthreads();
    const int jl = tid >> 2, c16 = (tid & 3) * 16;
    u16* dst = xbf + ((size_t)fl * 4096 + n0 + jl) * 256 + c0 + c16;
    u16x8 a, bv;
    #pragma unroll
    for (int i = 0; i < 8; ++i) a[i] = f2bf(T[c16 + i][jl]);
    #pragma unroll
    for (int i = 0; i < 8; ++i) bv[i] = f2bf(T[c16 + 8 + i][jl]);
    *(u16x8*)dst = a;
    *(u16x8*)(dst + 8) = bv;
}

// ---------------- C1: w_qkv f32 -> bf16 (same layout) -----------------------
__global__ __launch_bounds__(256) void k_cvt_w(const float* __restrict__ w,
                                               u16* __restrict__ wbf)
{
    const int i = (blockIdx.x * 256 + threadIdx.x) * 8;
    u16x8 o;
    #pragma unroll
    for (int j = 0; j < 8; ++j) o[j] = f2bf(w[i + j]);
    *(u16x8*)(wbf + i) = o;
}

// ---------------- K1: qkv_t[j][o] = A(wq)[o][c] * B(x)[j][c], bf16 out ------
// M = o (A side), N = j (B side). 128x128 tile, BK=32, K=256.
__global__ __launch_bounds__(256) void k_qkv_mfma(const u16* __restrict__ xbf,
                                                  const u16* __restrict__ wq,
                                                  u16* __restrict__ qkv)
{
    const int tid = threadIdx.x;
    const int lane = tid & 63, wave = tid >> 6;
    const int ln = lane & 15, quad = lane >> 4;
    const int wm = wave & 1, wn = wave >> 1;
    const int j0 = blockIdx.x * 128;   // N tile (x rows)
    const int o0 = blockIdx.y * 128;   // M tile (wq rows)

    __shared__ __align__(16) u16 sm[128 * 136];  // 34816 B; staging overlaid
    u16* As = sm;             // [128 o][32 k]
    u16* Bs = sm + 4096;      // [128 j][32 k]

    f32x4 acc[4][4] = {};
    const int lrow = lane >> 2;        // 0..15
    const int lk8 = (lane & 3) * 8;    // k element offset within BK

    for (int kk = 0; kk < 256; kk += 32) {
        __syncthreads();
        #pragma unroll
        for (int p = 0; p < 2; ++p) {
            const int chunk = wave * 2 + p;
            const int r = chunk * 16 + lrow;
            async16(wq  + (size_t)(o0 + r) * 256 + kk + lk8, As + chunk * 512);
            async16(xbf + (size_t)(j0 + r) * 256 + kk + lk8, Bs + chunk * 512);
        }
        __syncthreads();
        bf16x8 af[4], bfv[4];
        #pragma unroll
        for (int mi = 0; mi < 4; ++mi)
            af[mi] = *(const bf16x8*)&As[(wm * 64 + mi * 16 + ln) * 32 + quad * 8];
        #pragma unroll
        for (int ni = 0; ni < 4; ++ni)
            bfv[ni] = *(const bf16x8*)&Bs[(wn * 64 + ni * 16 + ln) * 32 + quad * 8];
        #pragma unroll
        for (int mi = 0; mi < 4; ++mi)
            #pragma unroll
            for (int ni = 0; ni < 4; ++ni)
                acc[mi][ni] = __builtin_amdgcn_mfma_f32_16x16x32_bf16(
                    af[mi], bfv[ni], acc[mi][ni], 0, 0, 0);
    }

    // Epilogue: assemble [j][o] bf16 tile in LDS (stride 136), coalesced store
    __syncthreads();
    u16* outl = sm;
    #pragma unroll
    for (int mi = 0; mi < 4; ++mi)
        #pragma unroll
        for (int ni = 0; ni < 4; ++ni) {
            const int jl = wn * 64 + ni * 16 + ln;
            const int ob = wm * 64 + mi * 16 + quad * 4;
            u16x4 u;
            u[0] = f2bf(acc[mi][ni][0]); u[1] = f2bf(acc[mi][ni][1]);
            u[2] = f2bf(acc[mi][ni][2]); u[3] = f2bf(acc[mi][ni][3]);
            *(u16x4*)&outl[jl * 136 + ob] = u;
        }
    __syncthreads();
    #pragma unroll
    for (int r = 0; r < 8; ++r) {
        const int row = r * 16 + (tid >> 4);
        const int cb = (tid & 15) * 8;
        u32x4 v = *(const u32x4*)&outl[row * 136 + cb];
        *(u32x4*)(qkv + (size_t)(j0 + row) * 768 + o0 + cb) = v;
    }
}

// ---------------- K2: softmax over j (4096) for k cols, per (fl,h,d) --------
__global__ __launch_bounds__(256) void k_softmax_k(u16* __restrict__ qkv)
{
    const int h = blockIdx.x, fl = blockIdx.y;
    const int tid = threadIdx.x;
    u16* base = qkv + (size_t)fl * 4096 * 768 + 256 + h * 32;
    const int d4 = (tid & 7) * 4, jj = tid >> 3;  // jj 0..31

    __shared__ float red[32 * 33 + 32];
    float* Lm  = red;
    float* Rsc = red + 32 * 33;

    float m[4] = {-1e30f, -1e30f, -1e30f, -1e30f};
    for (int it = 0; it < 128; ++it) {
        const u16x4 u = *(const u16x4*)(base + (size_t)(jj + it * 32) * 768 + d4);
        #pragma unroll
        for (int i = 0; i < 4; ++i) m[i] = fmaxf(m[i], bf2f(u[i]));
    }
    #pragma unroll
    for (int i = 0; i < 4; ++i) Lm[jj * 33 + d4 + i] = m[i];
    __syncthreads();
    if (tid < 32) {
        float M = -1e30f;
        for (int k = 0; k < 32; ++k) M = fmaxf(M, Lm[k * 33 + tid]);
        Rsc[tid] = M;
    }
    __syncthreads();
    float Mv[4];
    #pragma unroll
    for (int i = 0; i < 4; ++i) Mv[i] = Rsc[d4 + i];
    __syncthreads();

    float s[4] = {0.f, 0.f, 0.f, 0.f};
    for (int it = 0; it < 128; ++it) {
        const u16x4 u = *(const u16x4*)(base + (size_t)(jj + it * 32) * 768 + d4);
        #pragma unroll
        for (int i = 0; i < 4; ++i) s[i] += __expf(bf2f(u[i]) - Mv[i]);
    }
    #pragma unroll
    for (int i = 0; i < 4; ++i) Lm[jj * 33 + d4 + i] = s[i];
    __syncthreads();
    if (tid < 32) {
        float S = 0.f;
        for (int k = 0; k < 32; ++k) S += Lm[k * 33 + tid];
        Rsc[tid] = 1.0f / S;
    }
    __syncthreads();
    float Iv[4];
    #pragma unroll
    for (int i = 0; i < 4; ++i) Iv[i] = Rsc[d4 + i];

    for (int it = 0; it < 128; ++it) {
        u16* p = base + (size_t)(jj + it * 32) * 768 + d4;
        u16x4 u = *(const u16x4*)p;
        u16x4 o;
        #pragma unroll
        for (int i = 0; i < 4; ++i) o[i] = f2bf(__expf(bf2f(u[i]) - Mv[i]) * Iv[i]);
        *(u16x4*)p = o;
    }
}

// ---------------- K3: softmax over d (32) for q, row-local, * scale ---------
__global__ __launch_bounds__(256) void k_softmax_q(u16* __restrict__ qkv)
{
    const int tid = threadIdx.x;
    const int j = blockIdx.x * 32 + (tid >> 3);
    const int h = tid & 7;
    u16* p = qkv + (size_t)j * 768 + h * 32;
    u16x8 u[4];
    #pragma unroll
    for (int g = 0; g < 4; ++g) u[g] = *(const u16x8*)(p + g * 8);
    float v[32];
    float m = -1e30f;
    #pragma unroll
    for (int g = 0; g < 4; ++g)
        #pragma unroll
        for (int i = 0; i < 8; ++i) { v[g * 8 + i] = bf2f(u[g][i]); m = fmaxf(m, v[g * 8 + i]); }
    float s = 0.f;
    #pragma unroll
    for (int i = 0; i < 32; ++i) { v[i] = __expf(v[i] - m); s += v[i]; }
    const float inv = 0.17677669529663687f / s;  // scale = 32^-0.5
    #pragma unroll
    for (int g = 0; g < 4; ++g) {
        u16x8 o;
        #pragma unroll
        for (int i = 0; i < 8; ++i) o[i] = f2bf(v[g * 8 + i] * inv);
        *(u16x8*)(p + g * 8) = o;
    }
}

// ---------------- K4: context (fp32) + fold into W2 (bf16 out) --------------
__global__ __launch_bounds__(256) void k_context_w2(const u16* __restrict__ qkv,
                                                    const float* __restrict__ w_out,
                                                    u16* __restrict__ w2)
{
    const int h = blockIdx.x, fl = blockIdx.y;
    const int tid = threadIdx.x;
    __shared__ float Ks[64 * 36], Vs[64 * 36], Cs[32 * 33];

    const int d = tid >> 3, e4 = (tid & 7) * 4;
    const int lr = tid >> 2, lc8 = (tid & 3) * 8;
    float acc[4] = {0.f, 0.f, 0.f, 0.f};
    const u16* kcol = qkv + (size_t)fl * 4096 * 768 + 256 + h * 32 + lc8;

    for (int jt = 0; jt < 4096; jt += 64) {
        const u16* kp = kcol + (size_t)(jt + lr) * 768;
        u16x8 ku = *(const u16x8*)kp;
        u16x8 vu = *(const u16x8*)(kp + 256);
        __syncthreads();
        #pragma unroll
        for (int i = 0; i < 8; ++i) {
            Ks[lr * 36 + lc8 + i] = bf2f(ku[i]);
            Vs[lr * 36 + lc8 + i] = bf2f(vu[i]);
        }
        __syncthreads();
        #pragma unroll 8
        for (int jr = 0; jr < 64; ++jr) {
            const float kd = Ks[jr * 36 + d];
            const f32x4 vv = *(const f32x4*)&Vs[jr * 36 + e4];
            acc[0] = fmaf(kd, vv[0], acc[0]);
            acc[1] = fmaf(kd, vv[1], acc[1]);
            acc[2] = fmaf(kd, vv[2], acc[2]);
            acc[3] = fmaf(kd, vv[3], acc[3]);
        }
    }
    __syncthreads();
    #pragma unroll
    for (int i = 0; i < 4; ++i) Cs[d * 33 + e4 + i] = acc[i];
    __syncthreads();

    // W2[o][h*32+dd] = sum_e w_out[o][h*32+e] * Cs[dd][e];  o = tid
    const int o = tid;
    float a2[32];
    #pragma unroll
    for (int dd = 0; dd < 32; ++dd) a2[dd] = 0.f;
    for (int e = 0; e < 32; ++e) {
        const float wv = w_out[(size_t)o * 256 + h * 32 + e];
        #pragma unroll
        for (int dd = 0; dd < 32; ++dd) a2[dd] = fmaf(wv, Cs[dd * 33 + e], a2[dd]);
    }
    u16* wp = w2 + (size_t)fl * 65536 + (size_t)o * 256 + h * 32;
    #pragma unroll
    for (int g = 0; g < 4; ++g) {
        u16x8 ov;
        #pragma unroll
        for (int i = 0; i < 8; ++i) ov[i] = f2bf(a2[g * 8 + i]);
        *(u16x8*)(wp + g * 8) = ov;
    }
}

// ---------------- K5: out[o][n] = A(q)[j][c2] * B(W2)[o][c2] + b_out --------
// M = j (A side), N = o (B side). 128x128 tile, BK=32, K=256. fp32 store.
__global__ __launch_bounds__(256) void k_out_mfma(const u16* __restrict__ qkv,
                                                  const u16* __restrict__ w2,
                                                  const float* __restrict__ b_out,
                                                  float* __restrict__ out, int fr0)
{
    const int tid = threadIdx.x;
    const int lane = tid & 63, wave = tid >> 6;
    const int ln = lane & 15, quad = lane >> 4;
    const int wm = wave & 1, wn = wave >> 1;
    const int j0 = blockIdx.x * 128;   // M tile (q rows, local j)
    const int o0 = blockIdx.y * 128;   // N tile (W2 rows)
    const int fl = j0 >> 12;
    const int frame = fr0 + fl, b = frame >> 4, f = frame & 15;
    const int nb = j0 & 4095;
    const u16* w2f = w2 + (size_t)fl * 65536;

    __shared__ __align__(16) u16 sm[8192];  // 16 KB staging
    u16* As = sm;             // [128 j][32 k]
    u16* Bs = sm + 4096;      // [128 o][32 k]

    f32x4 acc[4][4] = {};
    const int lrow = lane >> 2;
    const int lk8 = (lane & 3) * 8;

    for (int kk = 0; kk < 256; kk += 32) {
        __syncthreads();
        #pragma unroll
        for (int p = 0; p < 2; ++p) {
            const int chunk = wave * 2 + p;
            const int r = chunk * 16 + lrow;
            async16(qkv + (size_t)(j0 + r) * 768 + kk + lk8, As + chunk * 512);
            async16(w2f + (size_t)(o0 + r) * 256 + kk + lk8, Bs + chunk * 512);
        }
        __syncthreads();
        bf16x8 af[4], bfv[4];
        #pragma unroll
        for (int mi = 0; mi < 4; ++mi)
            af[mi] = *(const bf16x8*)&As[(wm * 64 + mi * 16 + ln) * 32 + quad * 8];
        #pragma unroll
        for (int ni = 0; ni < 4; ++ni)
            bfv[ni] = *(const bf16x8*)&Bs[(wn * 64 + ni * 16 + ln) * 32 + quad * 8];
        #pragma unroll
        for (int mi = 0; mi < 4; ++mi)
            #pragma unroll
            for (int ni = 0; ni < 4; ++ni)
                acc[mi][ni] = __builtin_amdgcn_mfma_f32_16x16x32_bf16(
                    af[mi], bfv[ni], acc[mi][ni], 0, 0, 0);
    }

    // Direct fp32 store: lane's 4 regs = consecutive j (=n) -> float4
    float* obase = out + (size_t)b * XB_STRIDE + (size_t)f * 4096;
    #pragma unroll
    for (int ni = 0; ni < 4; ++ni) {
        const int o = o0 + wn * 64 + ni * 16 + ln;
        const float bias = b_out[o];
        #pragma unroll
        for (int mi = 0; mi < 4; ++mi) {
            const int jn = nb + wm * 64 + mi * 16 + quad * 4;
            f32x4 v = acc[mi][ni];
            v[0] += bias; v[1] += bias; v[2] += bias; v[3] += bias;
            *(f32x4*)(obase + (size_t)o * XCH_STRIDE + jn) = v;
        }
    }
}

// ---------------------------------------------------------------------------
extern "C" void kernel_launch(void* const* d_in, const int* in_sizes, int n_in,
                              void* d_out, int out_size, void* d_ws, size_t ws_size,
                              hipStream_t stream)
{
    const float* x     = (const float*)d_in[0];
    const float* w_qkv = (const float*)d_in[1];
    const float* w_out = (const float*)d_in[2];
    const float* b_out = (const float*)d_in[3];
    float* out = (float*)d_out;

    // ws per frame: xbf 4096*256*2 + qkv 4096*768*2 + w2 65536*2 = 8,519,680 B
    const size_t per_frame = (size_t)4096 * 256 * 2 + (size_t)4096 * 768 * 2 + 65536 * 2;
    const size_t wq_bytes = 768 * 256 * 2;
    int CF = 32;
    while (CF > 1 && (size_t)CF * per_frame + wq_bytes > ws_size) CF >>= 1;

    u16* wq_bf = (u16*)d_ws;
    u16* xbf   = wq_bf + 768 * 256;
    u16* qkv   = xbf + (size_t)CF * 4096 * 256;
    u16* w2    = qkv + (size_t)CF * 4096 * 768;

    k_cvt_w<<<96, 256, 0, stream>>>(w_qkv, wq_bf);
    for (int fr0 = 0; fr0 < 32; fr0 += CF) {
        k_cvt_x    <<<dim3(64, 4, CF), 256, 0, stream>>>(x, xbf, fr0);
        k_qkv_mfma <<<dim3(CF * 32, 6), 256, 0, stream>>>(xbf, wq_bf, qkv);
        k_softmax_k<<<dim3(8, CF),     256, 0, stream>>>(qkv);
        k_softmax_q<<<dim3(CF * 128),  256, 0, stream>>>(qkv);
        k_context_w2<<<dim3(8, CF),    256, 0, stream>>>(qkv, w_out, w2);
        k_out_mfma <<<dim3(CF * 32, 2), 256, 0, stream>>>(qkv, w2, b_out, out, fr0);
    }
}

// Round 3
// 485.778 us; speedup vs baseline: 2.8223x; 1.2029x over previous
//
#include <hip/hip_runtime.h>
#include <cmath>

// ---------------------------------------------------------------------------
// SpatialLinearAttention — bf16 MFMA GEMMs + fused softmax/context chain.
//   x:(2,256,16,64,64) f32, w_qkv:(768,256) f32, w_out:(256,256) f32, b_out:(256,)
// Per chunk of CF frames (j = fl*4096 + n):
//   C0: xbf_t[j][c] = bf16(x^T)                      (k-contiguous)
//   C1: wq_bf = bf16(w_qkv)                          (once)
//   K1: qkv_t[j][o] = MFMA(wq[o][c], xbf[j][c]); q tiles (o<256) get the
//       d-softmax (*1/sqrt(32)) fused in the epilogue.  k,v stored raw bf16.
//   S1: k_kstat1: per (fl, j-split): online (m,s) partials per k-col (256)
//   S2: k_kstat2: combine 16 partials -> (M, 1/S) per (fl, k-col)
//   CX: k_ctx: per (fl, j-split): P[h][d][e] += exp(k[d,j]-M_d) * v[e,j]
//   W2: k_w2fold: C = invS_d * sum_js P; W2[o][h*32+d] = sum_e w_out[o][..e]*C[d][e]
//   K5: out = MFMA(q[j][c2], W2[o][c2]) + b_out, fp32 direct store
// ---------------------------------------------------------------------------

typedef unsigned short u16;
typedef __attribute__((ext_vector_type(4))) unsigned short u16x4;
typedef __attribute__((ext_vector_type(8))) unsigned short u16x8;
typedef __attribute__((ext_vector_type(4))) unsigned int   u32x4;
typedef __attribute__((ext_vector_type(8))) short bf16x8;
typedef __attribute__((ext_vector_type(4))) float f32x4;

#define XCH_STRIDE 65536    // x stride over c: 16*4096
#define XB_STRIDE  16777216 // x stride over b: 256*16*4096

__device__ __forceinline__ float bf2f(u16 u) {
    union { unsigned int i; float f; } w; w.i = ((unsigned int)u) << 16; return w.f;
}
__device__ __forceinline__ u16 f2bf(float f) {
    union { float f; unsigned int i; } w; w.f = f;
    return (u16)((w.i + 0x7FFFu + ((w.i >> 16) & 1u)) >> 16);
}
__device__ __forceinline__ void async16(const void* g, void* l) {
    __builtin_amdgcn_global_load_lds(
        (const __attribute__((address_space(1))) unsigned int*)g,
        (__attribute__((address_space(3))) unsigned int*)l, 16, 0, 0);
}

// ---------------- C0: x (b,c,f,n) f32 -> xbf_t[(fl,n)][c] bf16 --------------
__global__ __launch_bounds__(256) void k_cvt_x(const float* __restrict__ x,
                                               u16* __restrict__ xbf, int fr0)
{
    const int tid = threadIdx.x;
    const int n0 = blockIdx.x * 64;
    const int c0 = blockIdx.y * 64;
    const int fl = blockIdx.z;
    const int frame = fr0 + fl, b = frame >> 4, f = frame & 15;
    const float* xb = x + (size_t)b * XB_STRIDE + (size_t)f * 4096;
    __shared__ float T[64][65];
    const int nn = tid & 63, cq = tid >> 6;
    #pragma unroll
    for (int r = 0; r < 16; ++r) {
        const int cl = r * 4 + cq;
        T[cl][nn] = xb[(size_t)(c0 + cl) * XCH_STRIDE + n0 + nn];
    }
    __syncthreads();
    const int jl = tid >> 2, c16 = (tid & 3) * 16;
    u16* dst = xbf + ((size_t)fl * 4096 + n0 + jl) * 256 + c0 + c16;
    u16x8 a, bv;
    #pragma unroll
    for (int i = 0; i < 8; ++i) a[i] = f2bf(T[c16 + i][jl]);
    #pragma unroll
    for (int i = 0; i < 8; ++i) bv[i] = f2bf(T[c16 + 8 + i][jl]);
    *(u16x8*)dst = a;
    *(u16x8*)(dst + 8) = bv;
}

// ---------------- C1: w_qkv f32 -> bf16 -------------------------------------
__global__ __launch_bounds__(256) void k_cvt_w(const float* __restrict__ w,
                                               u16* __restrict__ wbf)
{
    const int i = (blockIdx.x * 256 + threadIdx.x) * 8;
    u16x8 o;
    #pragma unroll
    for (int j = 0; j < 8; ++j) o[j] = f2bf(w[i + j]);
    *(u16x8*)(wbf + i) = o;
}

// ---------------- K1: qkv_t[j][o] MFMA, q-softmax fused in epilogue ---------
__global__ __launch_bounds__(256) void k_qkv_mfma(const u16* __restrict__ xbf,
                                                  const u16* __restrict__ wq,
                                                  u16* __restrict__ qkv)
{
    const int tid = threadIdx.x;
    const int lane = tid & 63, wave = tid >> 6;
    const int ln = lane & 15, quad = lane >> 4;
    const int wm = wave & 1, wn = wave >> 1;
    const int j0 = blockIdx.x * 128;   // N tile (x rows)
    const int o0 = blockIdx.y * 128;   // M tile (wq rows)

    __shared__ __align__(16) u16 sm[128 * 136];  // staging + out-tile overlaid
    u16* As = sm;             // [128 o][32 k]
    u16* Bs = sm + 4096;      // [128 j][32 k]

    f32x4 acc[4][4] = {};
    const int lrow = lane >> 2;
    const int lk8 = (lane & 3) * 8;

    for (int kk = 0; kk < 256; kk += 32) {
        __syncthreads();
        #pragma unroll
        for (int p = 0; p < 2; ++p) {
            const int chunk = wave * 2 + p;
            const int r = chunk * 16 + lrow;
            async16(wq  + (size_t)(o0 + r) * 256 + kk + lk8, As + chunk * 512);
            async16(xbf + (size_t)(j0 + r) * 256 + kk + lk8, Bs + chunk * 512);
        }
        __syncthreads();
        bf16x8 af[4], bfv[4];
        #pragma unroll
        for (int mi = 0; mi < 4; ++mi)
            af[mi] = *(const bf16x8*)&As[(wm * 64 + mi * 16 + ln) * 32 + quad * 8];
        #pragma unroll
        for (int ni = 0; ni < 4; ++ni)
            bfv[ni] = *(const bf16x8*)&Bs[(wn * 64 + ni * 16 + ln) * 32 + quad * 8];
        #pragma unroll
        for (int mi = 0; mi < 4; ++mi)
            #pragma unroll
            for (int ni = 0; ni < 4; ++ni)
                acc[mi][ni] = __builtin_amdgcn_mfma_f32_16x16x32_bf16(
                    af[mi], bfv[ni], acc[mi][ni], 0, 0, 0);
    }

    // Assemble [j][o] bf16 tile in LDS (stride 136)
    __syncthreads();
    u16* outl = sm;
    #pragma unroll
    for (int mi = 0; mi < 4; ++mi)
        #pragma unroll
        for (int ni = 0; ni < 4; ++ni) {
            const int jl = wn * 64 + ni * 16 + ln;
            const int ob = wm * 64 + mi * 16 + quad * 4;
            u16x4 u;
            u[0] = f2bf(acc[mi][ni][0]); u[1] = f2bf(acc[mi][ni][1]);
            u[2] = f2bf(acc[mi][ni][2]); u[3] = f2bf(acc[mi][ni][3]);
            *(u16x4*)&outl[jl * 136 + ob] = u;
        }
    __syncthreads();

    if (blockIdx.y < 2) {
        // q tiles: softmax over each 32-col head group, * 1/sqrt(32)
        #pragma unroll
        for (int t = 0; t < 2; ++t) {
            const int idx = t * 256 + tid;
            const int r = idx >> 2, hh = idx & 3;
            const u16* p = &outl[r * 136 + hh * 32];
            float v[32];
            float m = -1e30f;
            #pragma unroll
            for (int g = 0; g < 4; ++g) {
                u16x8 u = *(const u16x8*)(p + g * 8);
                #pragma unroll
                for (int i = 0; i < 8; ++i) {
                    v[g * 8 + i] = bf2f(u[i]);
                    m = fmaxf(m, v[g * 8 + i]);
                }
            }
            float s = 0.f;
            #pragma unroll
            for (int i = 0; i < 32; ++i) { v[i] = __expf(v[i] - m); s += v[i]; }
            const float inv = 0.17677669529663687f / s;
            u16* q = qkv + (size_t)(j0 + r) * 768 + o0 + hh * 32;
            #pragma unroll
            for (int g = 0; g < 4; ++g) {
                u16x8 ov;
                #pragma unroll
                for (int i = 0; i < 8; ++i) ov[i] = f2bf(v[g * 8 + i] * inv);
                *(u16x8*)(q + g * 8) = ov;
            }
        }
    } else {
        #pragma unroll
        for (int r = 0; r < 8; ++r) {
            const int row = r * 16 + (tid >> 4);
            const int cb = (tid & 15) * 8;
            u32x4 v = *(const u32x4*)&outl[row * 136 + cb];
            *(u32x4*)(qkv + (size_t)(j0 + row) * 768 + o0 + cb) = v;
        }
    }
}

// ---------------- S1: online (m,s) partials per k-col, per (fl, j-split) ----
__global__ __launch_bounds__(256) void k_kstat1(const u16* __restrict__ qkv,
                                                float* __restrict__ sp)
{
    const int js = blockIdx.x, fl = blockIdx.y;
    const int tid = threadIdx.x;
    const int s = tid >> 5, g = tid & 31;
    const u16* base = qkv + ((size_t)fl * 4096 + js * 256 + s) * 768 + 256 + g * 8;
    float m[8], sm[8];
    #pragma unroll
    for (int i = 0; i < 8; ++i) { m[i] = -1e30f; sm[i] = 0.f; }
    for (int it = 0; it < 32; ++it) {
        u16x8 u = *(const u16x8*)(base + (size_t)it * 8 * 768);
        #pragma unroll
        for (int i = 0; i < 8; ++i) {
            float v = bf2f(u[i]);
            float nm = fmaxf(m[i], v);
            sm[i] = sm[i] * __expf(m[i] - nm) + __expf(v - nm);
            m[i] = nm;
        }
    }
    __shared__ float Lm[8][256], Ls[8][256];
    #pragma unroll
    for (int i = 0; i < 8; ++i) { Lm[s][g * 8 + i] = m[i]; Ls[s][g * 8 + i] = sm[i]; }
    __syncthreads();
    const int col = tid;
    float M = -1e30f;
    #pragma unroll
    for (int k = 0; k < 8; ++k) M = fmaxf(M, Lm[k][col]);
    float S = 0.f;
    #pragma unroll
    for (int k = 0; k < 8; ++k) S += Ls[k][col] * __expf(Lm[k][col] - M);
    float* o = sp + (((size_t)fl * 16 + js) * 256 + col) * 2;
    o[0] = M; o[1] = S;
}

// ---------------- S2: combine 16 partials -> (M, 1/S) -----------------------
__global__ __launch_bounds__(256) void k_kstat2(const float* __restrict__ sp,
                                                float* __restrict__ stat)
{
    const int fl = blockIdx.x, col = threadIdx.x;
    float mv[16], sv[16];
    float M = -1e30f;
    #pragma unroll
    for (int js = 0; js < 16; ++js) {
        const float* p = sp + (((size_t)fl * 16 + js) * 256 + col) * 2;
        mv[js] = p[0]; sv[js] = p[1];
        M = fmaxf(M, mv[js]);
    }
    float S = 0.f;
    #pragma unroll
    for (int js = 0; js < 16; ++js) S += sv[js] * __expf(mv[js] - M);
    float* o = stat + ((size_t)fl * 256 + col) * 2;
    o[0] = M; o[1] = 1.0f / S;
}

// ---------------- CX: P[h][d][e] += exp(k-M)*v, per (fl, j-split) -----------
__global__ __launch_bounds__(256) void k_ctx(const u16* __restrict__ qkv,
                                             const float* __restrict__ stat,
                                             float* __restrict__ P)
{
    const int js = blockIdx.x, fl = blockIdx.y;
    const int tid = threadIdx.x;
    const int ls = tid >> 5, lg = tid & 31;                  // staging role
    const int h = tid >> 5, dg = (tid >> 3) & 3, eg = tid & 7;  // acc role
    const int d0 = dg * 8, e0 = eg * 4;

    float Mg[8];
    #pragma unroll
    for (int i = 0; i < 8; ++i) Mg[i] = stat[((size_t)fl * 256 + lg * 8 + i) * 2];

    __shared__ float expk[8][264], vbuf[8][264];
    f32x4 acc[8] = {};
    const u16* kbase = qkv + ((size_t)fl * 4096 + js * 256 + ls) * 768 + 256 + lg * 8;

    for (int ch = 0; ch < 32; ++ch) {
        const u16* kp = kbase + (size_t)ch * 8 * 768;
        u16x8 ku = *(const u16x8*)kp;
        u16x8 vu = *(const u16x8*)(kp + 256);
        __syncthreads();
        #pragma unroll
        for (int i = 0; i < 8; ++i) {
            expk[ls][lg * 8 + i] = __expf(bf2f(ku[i]) - Mg[i]);
            vbuf[ls][lg * 8 + i] = bf2f(vu[i]);
        }
        __syncthreads();
        #pragma unroll
        for (int rr = 0; rr < 8; ++rr) {
            f32x4 w0 = *(const f32x4*)&expk[rr][h * 32 + d0];
            f32x4 w1 = *(const f32x4*)&expk[rr][h * 32 + d0 + 4];
            f32x4 vv = *(const f32x4*)&vbuf[rr][h * 32 + e0];
            #pragma unroll
            for (int ei = 0; ei < 4; ++ei) {
                acc[0][ei] = fmaf(w0[0], vv[ei], acc[0][ei]);
                acc[1][ei] = fmaf(w0[1], vv[ei], acc[1][ei]);
                acc[2][ei] = fmaf(w0[2], vv[ei], acc[2][ei]);
                acc[3][ei] = fmaf(w0[3], vv[ei], acc[3][ei]);
                acc[4][ei] = fmaf(w1[0], vv[ei], acc[4][ei]);
                acc[5][ei] = fmaf(w1[1], vv[ei], acc[5][ei]);
                acc[6][ei] = fmaf(w1[2], vv[ei], acc[6][ei]);
                acc[7][ei] = fmaf(w1[3], vv[ei], acc[7][ei]);
            }
        }
    }
    float* o = P + ((size_t)fl * 16 + js) * 8192 + (h * 32 + d0) * 32 + e0;
    #pragma unroll
    for (int di = 0; di < 8; ++di) *(f32x4*)(o + di * 32) = acc[di];
}

// ---------------- W2: sum partials, *invS, fold w_out -> W2 bf16 ------------
__global__ __launch_bounds__(256) void k_w2fold(const float* __restrict__ P,
                                                const float* __restrict__ stat,
                                                const float* __restrict__ w_out,
                                                u16* __restrict__ w2)
{
    const int h = blockIdx.x, fl = blockIdx.y;
    const int tid = threadIdx.x;
    __shared__ float Cs[32 * 33];

    const float* p0 = P + (size_t)fl * 16 * 8192 + h * 1024 + tid * 4;
    f32x4 sum = {0.f, 0.f, 0.f, 0.f};
    #pragma unroll
    for (int js = 0; js < 16; ++js) {
        f32x4 v = *(const f32x4*)(p0 + (size_t)js * 8192);
        sum[0] += v[0]; sum[1] += v[1]; sum[2] += v[2]; sum[3] += v[3];
    }
    const int d = tid >> 3, e4 = (tid & 7) * 4;
    const float inv = stat[((size_t)fl * 256 + h * 32 + d) * 2 + 1];
    Cs[d * 33 + e4 + 0] = sum[0] * inv;
    Cs[d * 33 + e4 + 1] = sum[1] * inv;
    Cs[d * 33 + e4 + 2] = sum[2] * inv;
    Cs[d * 33 + e4 + 3] = sum[3] * inv;
    __syncthreads();

    const int o = tid;
    float a2[32];
    #pragma unroll
    for (int dd = 0; dd < 32; ++dd) a2[dd] = 0.f;
    for (int e = 0; e < 32; ++e) {
        const float wv = w_out[(size_t)o * 256 + h * 32 + e];
        #pragma unroll
        for (int dd = 0; dd < 32; ++dd) a2[dd] = fmaf(wv, Cs[dd * 33 + e], a2[dd]);
    }
    u16* wp = w2 + (size_t)fl * 65536 + (size_t)o * 256 + h * 32;
    #pragma unroll
    for (int g = 0; g < 4; ++g) {
        u16x8 ov;
        #pragma unroll
        for (int i = 0; i < 8; ++i) ov[i] = f2bf(a2[g * 8 + i]);
        *(u16x8*)(wp + g * 8) = ov;
    }
}

// ---------------- K5: out = MFMA(q, W2) + b_out, fp32 direct store ----------
__global__ __launch_bounds__(256) void k_out_mfma(const u16* __restrict__ qkv,
                                                  const u16* __restrict__ w2,
                                                  const float* __restrict__ b_out,
                                                  float* __restrict__ out, int fr0)
{
    const int tid = threadIdx.x;
    const int lane = tid & 63, wave = tid >> 6;
    const int ln = lane & 15, quad = lane >> 4;
    const int wm = wave & 1, wn = wave >> 1;
    const int j0 = blockIdx.x * 128;   // M tile (q rows, local j)
    const int o0 = blockIdx.y * 128;   // N tile (W2 rows)
    const int fl = j0 >> 12;
    const int frame = fr0 + fl, b = frame >> 4, f = frame & 15;
    const int nb = j0 & 4095;
    const u16* w2f = w2 + (size_t)fl * 65536;

    __shared__ __align__(16) u16 sm[8192];
    u16* As = sm;
    u16* Bs = sm + 4096;

    f32x4 acc[4][4] = {};
    const int lrow = lane >> 2;
    const int lk8 = (lane & 3) * 8;

    for (int kk = 0; kk < 256; kk += 32) {
        __syncthreads();
        #pragma unroll
        for (int p = 0; p < 2; ++p) {
            const int chunk = wave * 2 + p;
            const int r = chunk * 16 + lrow;
            async16(qkv + (size_t)(j0 + r) * 768 + kk + lk8, As + chunk * 512);
            async16(w2f + (size_t)(o0 + r) * 256 + kk + lk8, Bs + chunk * 512);
        }
        __syncthreads();
        bf16x8 af[4], bfv[4];
        #pragma unroll
        for (int mi = 0; mi < 4; ++mi)
            af[mi] = *(const bf16x8*)&As[(wm * 64 + mi * 16 + ln) * 32 + quad * 8];
        #pragma unroll
        for (int ni = 0; ni < 4; ++ni)
            bfv[ni] = *(const bf16x8*)&Bs[(wn * 64 + ni * 16 + ln) * 32 + quad * 8];
        #pragma unroll
        for (int mi = 0; mi < 4; ++mi)
            #pragma unroll
            for (int ni = 0; ni < 4; ++ni)
                acc[mi][ni] = __builtin_amdgcn_mfma_f32_16x16x32_bf16(
                    af[mi], bfv[ni], acc[mi][ni], 0, 0, 0);
    }

    float* obase = out + (size_t)b * XB_STRIDE + (size_t)f * 4096;
    #pragma unroll
    for (int ni = 0; ni < 4; ++ni) {
        const int o = o0 + wn * 64 + ni * 16 + ln;
        const float bias = b_out[o];
        #pragma unroll
        for (int mi = 0; mi < 4; ++mi) {
            const int jn = nb + wm * 64 + mi * 16 + quad * 4;
            f32x4 v = acc[mi][ni];
            v[0] += bias; v[1] += bias; v[2] += bias; v[3] += bias;
            *(f32x4*)(obase + (size_t)o * XCH_STRIDE + jn) = v;
        }
    }
}

// ---------------------------------------------------------------------------
extern "C" void kernel_launch(void* const* d_in, const int* in_sizes, int n_in,
                              void* d_out, int out_size, void* d_ws, size_t ws_size,
                              hipStream_t stream)
{
    const float* x     = (const float*)d_in[0];
    const float* w_qkv = (const float*)d_in[1];
    const float* w_out = (const float*)d_in[2];
    const float* b_out = (const float*)d_in[3];
    float* out = (float*)d_out;

    // ws per frame: xbf 2MB + qkv 6MB + w2 128KB + sp 32KB + stat 2KB + P 512KB
    const size_t per_frame = (size_t)4096 * 256 * 2 + (size_t)4096 * 768 * 2
                           + 65536 * 2 + 16 * 512 * 4 + 512 * 4 + 16 * 8192 * 4;
    const size_t wq_bytes = 768 * 256 * 2;
    int CF = 32;
    while (CF > 1 && (size_t)CF * per_frame + wq_bytes > ws_size) CF >>= 1;

    u16* wq_bf  = (u16*)d_ws;
    u16* xbf    = wq_bf + 768 * 256;
    u16* qkv    = xbf + (size_t)CF * 4096 * 256;
    u16* w2     = qkv + (size_t)CF * 4096 * 768;
    float* sp   = (float*)(w2 + (size_t)CF * 65536);
    float* stat = sp + (size_t)CF * 16 * 256 * 2;
    float* P    = stat + (size_t)CF * 256 * 2;

    k_cvt_w<<<96, 256, 0, stream>>>(w_qkv, wq_bf);
    for (int fr0 = 0; fr0 < 32; fr0 += CF) {
        k_cvt_x   <<<dim3(64, 4, CF), 256, 0, stream>>>(x, xbf, fr0);
        k_qkv_mfma<<<dim3(CF * 32, 6), 256, 0, stream>>>(xbf, wq_bf, qkv);
        k_kstat1  <<<dim3(16, CF), 256, 0, stream>>>(qkv, sp);
        k_kstat2  <<<CF, 256, 0, stream>>>(sp, stat);
        k_ctx     <<<dim3(16, CF), 256, 0, stream>>>(qkv, stat, P);
        k_w2fold  <<<dim3(8, CF), 256, 0, stream>>>(P, stat, w_out, w2);
        k_out_mfma<<<dim3(CF * 32, 2), 256, 0, stream>>>(qkv, w2, b_out, out, fr0);
    }
}